// Round 1
// baseline (663.336 us; speedup 1.0000x reference)
//
#include <hip/hip_runtime.h>
#include <math.h>

#define D 128
#define G4 512          // 4*D gates
#define BATCH 4096
#define TEM_LEN 4
#define REL_TOTAL 500
#define TEM_TOTAL 32
#define NSTEP 5         // 1 rel + 4 tem tokens
#define BT 16           // batch rows per block

__device__ __forceinline__ float fsigmoid(float x) {
    // overflow-safe: x->-inf: exp->inf -> 0 ; x->+inf: exp->0 -> 1
    return 1.0f / (1.0f + __expf(-x));
}
__device__ __forceinline__ float ftanh(float x) {
    // overflow-safe: x->+inf: exp->inf -> 1 ; x->-inf: exp->0 -> -1
    return 1.0f - 2.0f / (__expf(2.0f * x) + 1.0f);
}

// ---------------------------------------------------------------------------
// Kernel A: xg rows for all 500 rel + 32 tem distinct embeddings.
// ws layout (floats): [0, 500*512) = rel_xg ; [500*512, 532*512) = tem_xg
// ---------------------------------------------------------------------------
__global__ __launch_bounds__(512) void precompute_xg(
    const float* __restrict__ rel_emb, const float* __restrict__ tem_emb,
    const float* __restrict__ W_ih, const float* __restrict__ b_ih,
    const float* __restrict__ b_hh, float* __restrict__ xg)
{
    __shared__ float srow[D];
    const int row = blockIdx.x;  // 0..531
    const float* src = (row < REL_TOTAL) ? (rel_emb + row * D)
                                         : (tem_emb + (row - REL_TOTAL) * D);
    const int tid = threadIdx.x;
    if (tid < D) srow[tid] = src[tid];
    __syncthreads();

    const int g = tid;  // one gate per thread (512 gates)
    const float4* w = (const float4*)(W_ih + g * D);
    float acc = b_ih[g] + b_hh[g];
#pragma unroll
    for (int j = 0; j < D / 4; ++j) {
        float4 wv = w[j];
        float4 hv = *(const float4*)(&srow[4 * j]);   // LDS broadcast
        acc += wv.x * hv.x + wv.y * hv.y + wv.z * hv.z + wv.w * hv.w;
    }
    xg[row * G4 + g] = acc;
}

// ---------------------------------------------------------------------------
// Kernel B: per-block LSTM over 16 batch rows (all 5 steps, no grid sync
// needed: recurrence is independent per batch row) + L1 TransE score.
// 256 blocks x 512 threads = 1 block/CU, 8 waves/CU.
// ---------------------------------------------------------------------------
__global__ __launch_bounds__(512) void lstm_score(
    const int* __restrict__ pos_h, const int* __restrict__ pos_t,
    const int* __restrict__ pos_r, const int* __restrict__ pos_tem,
    const int* __restrict__ neg_h, const int* __restrict__ neg_t,
    const float* __restrict__ ent_emb, const float* __restrict__ W_hh,
    const float* __restrict__ xg, float* __restrict__ out)
{
    __shared__ float sh[BT][D];        // 8 KB  hidden
    __shared__ float scell[BT][D];     // 8 KB  cell
    __shared__ float sg[BT][G4];       // 32 KB gates
    __shared__ int   soff[NSTEP][BT];  // xg row offsets (floats)

    const int tid = threadIdx.x;
    const int b0 = blockIdx.x * BT;

    // xg row offset per (step, batch-row)
    if (tid < NSTEP * BT) {
        int t = tid / BT, r = tid % BT;
        int off;
        if (t == 0) off = pos_r[b0 + r] * G4;
        else        off = (REL_TOTAL + pos_tem[(b0 + r) * TEM_LEN + (t - 1)]) * G4;
        soff[t][r] = off;
    }
    // zero h, c
    for (int i = tid; i < BT * D; i += 512) {
        ((float*)sh)[i] = 0.0f;
        ((float*)scell)[i] = 0.0f;
    }
    __syncthreads();

    const int g = tid;  // this thread's gate row
    const float4* wrow = (const float4*)(W_hh + g * D);

    for (int t = 0; t < NSTEP; ++t) {
        float acc[BT];
#pragma unroll
        for (int r = 0; r < BT; ++r) acc[r] = xg[soff[t][r] + g];  // coalesced

        if (t > 0) {  // t==0: h==0, dot contributes nothing
#pragma unroll
            for (int kc = 0; kc < 4; ++kc) {       // K chunks of 32
                float4 w[8];
#pragma unroll
                for (int j = 0; j < 8; ++j) w[j] = wrow[kc * 8 + j];
#pragma unroll
                for (int r = 0; r < BT; ++r) {
#pragma unroll
                    for (int j = 0; j < 8; ++j) {
                        // all lanes same address -> LDS broadcast, free
                        float4 hv = *(const float4*)(&sh[r][kc * 32 + 4 * j]);
                        acc[r] += w[j].x * hv.x + w[j].y * hv.y
                                + w[j].z * hv.z + w[j].w * hv.w;
                    }
                }
            }
        }
#pragma unroll
        for (int r = 0; r < BT; ++r) sg[r][g] = acc[r];
        __syncthreads();

        // activation + state update: 2048 (row,d) elems, 4 per thread
#pragma unroll
        for (int i = 0; i < 4; ++i) {
            int e = tid + i * 512;
            int r = e >> 7, d = e & (D - 1);
            float xi = sg[r][d];
            float xf = sg[r][D + d];
            float xc = sg[r][2 * D + d];
            float xo = sg[r][3 * D + d];
            float ii = fsigmoid(xi), ff = fsigmoid(xf);
            float gg = ftanh(xc),   oo = fsigmoid(xo);
            float cc = ff * scell[r][d] + ii * gg;
            scell[r][d] = cc;
            sh[r][d] = oo * ftanh(cc);
        }
        __syncthreads();
    }

    // ---- score: 32 lanes per batch row, float4 per lane ----
    const int row  = tid >> 5;
    const int lane = tid & 31;
    const int b    = b0 + row;
    const int d0   = lane * 4;
    float4 hh  = *(const float4*)(&sh[row][d0]);
    float4 phe = *(const float4*)(ent_emb + (long long)pos_h[b] * D + d0);
    float4 pte = *(const float4*)(ent_emb + (long long)pos_t[b] * D + d0);
    float4 nhe = *(const float4*)(ent_emb + (long long)neg_h[b] * D + d0);
    float4 nte = *(const float4*)(ent_emb + (long long)neg_t[b] * D + d0);
    float ps = fabsf(phe.x + hh.x - pte.x) + fabsf(phe.y + hh.y - pte.y)
             + fabsf(phe.z + hh.z - pte.z) + fabsf(phe.w + hh.w - pte.w);
    float ns = fabsf(nhe.x + hh.x - nte.x) + fabsf(nhe.y + hh.y - nte.y)
             + fabsf(nhe.z + hh.z - nte.z) + fabsf(nhe.w + hh.w - nte.w);
#pragma unroll
    for (int off = 16; off >= 1; off >>= 1) {   // reduce within 32-lane group
        ps += __shfl_xor(ps, off, 64);
        ns += __shfl_xor(ns, off, 64);
    }
    if (lane == 0) {
        out[b] = ps;            // pos scores
        out[BATCH + b] = ns;    // neg scores
    }
}

extern "C" void kernel_launch(void* const* d_in, const int* in_sizes, int n_in,
                              void* d_out, int out_size, void* d_ws, size_t ws_size,
                              hipStream_t stream) {
    const int*   pos_h   = (const int*)d_in[0];
    const int*   pos_t   = (const int*)d_in[1];
    const int*   pos_r   = (const int*)d_in[2];
    const int*   pos_tem = (const int*)d_in[3];
    const int*   neg_h   = (const int*)d_in[4];
    const int*   neg_t   = (const int*)d_in[5];
    // d_in[6] neg_r, d_in[7] neg_tem: unused (score uses pos LSTM output)
    const float* ent_emb = (const float*)d_in[8];
    const float* rel_emb = (const float*)d_in[9];
    const float* tem_emb = (const float*)d_in[10];
    const float* W_ih    = (const float*)d_in[11];
    const float* W_hh    = (const float*)d_in[12];
    const float* b_ih    = (const float*)d_in[13];
    const float* b_hh    = (const float*)d_in[14];
    float* out = (float*)d_out;
    float* xg  = (float*)d_ws;  // (500+32)*512 floats = 1.06 MB

    precompute_xg<<<REL_TOTAL + TEM_TOTAL, 512, 0, stream>>>(
        rel_emb, tem_emb, W_ih, b_ih, b_hh, xg);
    lstm_score<<<BATCH / BT, 512, 0, stream>>>(
        pos_h, pos_t, pos_r, pos_tem, neg_h, neg_t, ent_emb, W_hh, xg, out);
}

// Round 2
// 658.908 us; speedup vs baseline: 1.0067x; 1.0067x over previous
//
#include <hip/hip_runtime.h>
#include <math.h>

#define D 128
#define G4 512          // 4*D gates
#define BATCH 4096
#define TEM_LEN 4
#define REL_TOTAL 500
#define TEM_TOTAL 32
#define NROWS (REL_TOTAL + TEM_TOTAL)   // 532 distinct xg rows
#define NSTEP 5         // 1 rel + 4 tem tokens
#define BT 8            // batch rows per block (lstm kernel)
#define XRPB 4          // xg rows per block (precompute kernel); 133*4 == 532

__device__ __forceinline__ float fsigmoid(float x) {
    return 1.0f / (1.0f + __expf(-x));       // overflow-safe both directions
}
__device__ __forceinline__ float ftanh(float x) {
    return 1.0f - 2.0f / (__expf(2.0f * x) + 1.0f);
}

// ---------------------------------------------------------------------------
// Kernel A: xg rows for all 500 rel + 32 tem distinct embeddings.
// 4 rows per block -> W_ih global traffic 136 MB -> 34 MB.
// ws layout (floats): [0, 500*512) = rel rows ; [500*512, 532*512) = tem rows
// ---------------------------------------------------------------------------
__global__ __launch_bounds__(512) void precompute_xg(
    const float* __restrict__ rel_emb, const float* __restrict__ tem_emb,
    const float* __restrict__ W_ih, const float* __restrict__ b_ih,
    const float* __restrict__ b_hh, float* __restrict__ xg)
{
    __shared__ float srow[XRPB][D];
    const int r0 = blockIdx.x * XRPB;           // 133 blocks * 4 = 532 exact
    const int tid = threadIdx.x;

    {   // stage 4 embedding rows (512 floats, one per thread)
        int rr = tid >> 7, dd = tid & (D - 1);
        int row = r0 + rr;
        const float* src = (row < REL_TOTAL) ? (rel_emb + row * D)
                                             : (tem_emb + (row - REL_TOTAL) * D);
        srow[rr][dd] = src[dd];
    }
    __syncthreads();

    const int g = tid;                           // one gate per thread
    const float4* w = (const float4*)(W_ih + g * D);
    const float b = b_ih[g] + b_hh[g];
    float a0 = b, a1 = b, a2 = b, a3 = b;
#pragma unroll
    for (int j = 0; j < D / 4; ++j) {
        float4 wv = w[j];
        float4 h0 = *(const float4*)(&srow[0][4 * j]);
        float4 h1 = *(const float4*)(&srow[1][4 * j]);
        float4 h2 = *(const float4*)(&srow[2][4 * j]);
        float4 h3 = *(const float4*)(&srow[3][4 * j]);
        a0 += wv.x * h0.x + wv.y * h0.y + wv.z * h0.z + wv.w * h0.w;
        a1 += wv.x * h1.x + wv.y * h1.y + wv.z * h1.z + wv.w * h1.w;
        a2 += wv.x * h2.x + wv.y * h2.y + wv.z * h2.z + wv.w * h2.w;
        a3 += wv.x * h3.x + wv.y * h3.y + wv.z * h3.z + wv.w * h3.w;
    }
    xg[(r0 + 0) * G4 + g] = a0;
    xg[(r0 + 1) * G4 + g] = a1;
    xg[(r0 + 2) * G4 + g] = a2;
    xg[(r0 + 3) * G4 + g] = a3;
}

// ---------------------------------------------------------------------------
// Kernel B: LSTM + score. Thread d owns ALL FOUR gates (i,f,g,o) of dim d:
//  - each ds_read_b128 of h feeds 16 FMAs (was 4) -> LDS pipe off critical path
//  - activations fully in-register, c never leaves registers
//  - no gate-transpose LDS array; double-buffered h -> 1 barrier/step
// 512 blocks x 128 threads, 8 batch rows per block.
// ---------------------------------------------------------------------------
__global__ __launch_bounds__(128) void lstm_score(
    const int* __restrict__ pos_h, const int* __restrict__ pos_t,
    const int* __restrict__ pos_r, const int* __restrict__ pos_tem,
    const int* __restrict__ neg_h, const int* __restrict__ neg_t,
    const float* __restrict__ ent_emb, const float* __restrict__ W_hh,
    const float* __restrict__ xg, float* __restrict__ out)
{
    __shared__ float hbuf[2][BT][D];   // 8 KB, double-buffered hidden state
    __shared__ int   soff[NSTEP][BT];  // xg row offsets (floats)

    const int tid = threadIdx.x;       // 0..127  == d
    const int b0 = blockIdx.x * BT;

    if (tid < NSTEP * BT) {
        int t = tid / BT, r = tid % BT;
        soff[t][r] = ((t == 0) ? pos_r[b0 + r]
                               : (REL_TOTAL + pos_tem[(b0 + r) * TEM_LEN + (t - 1)])) * G4;
    }
    __syncthreads();

    const int d = tid;
    float c[BT];
#pragma unroll
    for (int r = 0; r < BT; ++r) c[r] = 0.0f;

    // W_hh rows for gates i,f,g,o of dim d
    const float4* wq0 = (const float4*)(W_hh + (0 * D + d) * D);
    const float4* wq1 = (const float4*)(W_hh + (1 * D + d) * D);
    const float4* wq2 = (const float4*)(W_hh + (2 * D + d) * D);
    const float4* wq3 = (const float4*)(W_hh + (3 * D + d) * D);

    for (int t = 0; t < NSTEP; ++t) {
        float acc[BT][4];
#pragma unroll
        for (int r = 0; r < BT; ++r) {         // coalesced xg gather
            const float* x = xg + soff[t][r] + d;
            acc[r][0] = x[0];
            acc[r][1] = x[D];
            acc[r][2] = x[2 * D];
            acc[r][3] = x[3 * D];
        }

        if (t > 0) {                            // t==0: h==0
            const float (*hp)[D] = hbuf[(t - 1) & 1];
            for (int kc = 0; kc < 8; ++kc) {    // K chunks of 16
                float4 w0[4], w1[4], w2[4], w3[4];
#pragma unroll
                for (int j = 0; j < 4; ++j) {
                    w0[j] = wq0[kc * 4 + j];
                    w1[j] = wq1[kc * 4 + j];
                    w2[j] = wq2[kc * 4 + j];
                    w3[j] = wq3[kc * 4 + j];
                }
#pragma unroll
                for (int r = 0; r < BT; ++r) {
#pragma unroll
                    for (int j = 0; j < 4; ++j) {
                        // wave-uniform address -> LDS broadcast; 16 FMAs per read
                        float4 hv = *(const float4*)(&hp[r][kc * 16 + 4 * j]);
                        acc[r][0] += w0[j].x * hv.x + w0[j].y * hv.y + w0[j].z * hv.z + w0[j].w * hv.w;
                        acc[r][1] += w1[j].x * hv.x + w1[j].y * hv.y + w1[j].z * hv.z + w1[j].w * hv.w;
                        acc[r][2] += w2[j].x * hv.x + w2[j].y * hv.y + w2[j].z * hv.z + w2[j].w * hv.w;
                        acc[r][3] += w3[j].x * hv.x + w3[j].y * hv.y + w3[j].z * hv.z + w3[j].w * hv.w;
                    }
                }
            }
        }

        // in-register activations; write h to the other buffer
#pragma unroll
        for (int r = 0; r < BT; ++r) {
            float ii = fsigmoid(acc[r][0]);
            float ff = fsigmoid(acc[r][1]);
            float gg = ftanh(acc[r][2]);
            float oo = fsigmoid(acc[r][3]);
            float cc = ff * c[r] + ii * gg;
            c[r] = cc;
            hbuf[t & 1][r][d] = oo * ftanh(cc);
        }
        __syncthreads();
    }

    // ---- score: 16 lanes per batch row, 8 dims (2 float4) per lane ----
    const float (*hf)[D] = hbuf[(NSTEP - 1) & 1];
    const int r  = tid >> 4;
    const int s  = tid & 15;
    const int b  = b0 + r;
    const int d0 = s * 8;
    const float4* ph = (const float4*)(ent_emb + (size_t)pos_h[b] * D + d0);
    const float4* pt = (const float4*)(ent_emb + (size_t)pos_t[b] * D + d0);
    const float4* nh = (const float4*)(ent_emb + (size_t)neg_h[b] * D + d0);
    const float4* nt = (const float4*)(ent_emb + (size_t)neg_t[b] * D + d0);
    float ps = 0.0f, ns = 0.0f;
#pragma unroll
    for (int u = 0; u < 2; ++u) {
        float4 hh = *(const float4*)(&hf[r][d0 + 4 * u]);
        float4 a = ph[u], bb = pt[u], cg = nh[u], dd = nt[u];
        ps += fabsf(a.x + hh.x - bb.x) + fabsf(a.y + hh.y - bb.y)
            + fabsf(a.z + hh.z - bb.z) + fabsf(a.w + hh.w - bb.w);
        ns += fabsf(cg.x + hh.x - dd.x) + fabsf(cg.y + hh.y - dd.y)
            + fabsf(cg.z + hh.z - dd.z) + fabsf(cg.w + hh.w - dd.w);
    }
#pragma unroll
    for (int off = 8; off >= 1; off >>= 1) {    // reduce within 16-lane group
        ps += __shfl_xor(ps, off, 64);
        ns += __shfl_xor(ns, off, 64);
    }
    if (s == 0) {
        out[b] = ps;            // pos scores
        out[BATCH + b] = ns;    // neg scores
    }
}

extern "C" void kernel_launch(void* const* d_in, const int* in_sizes, int n_in,
                              void* d_out, int out_size, void* d_ws, size_t ws_size,
                              hipStream_t stream) {
    const int*   pos_h   = (const int*)d_in[0];
    const int*   pos_t   = (const int*)d_in[1];
    const int*   pos_r   = (const int*)d_in[2];
    const int*   pos_tem = (const int*)d_in[3];
    const int*   neg_h   = (const int*)d_in[4];
    const int*   neg_t   = (const int*)d_in[5];
    // d_in[6] neg_r, d_in[7] neg_tem: unused (score uses pos LSTM output)
    const float* ent_emb = (const float*)d_in[8];
    const float* rel_emb = (const float*)d_in[9];
    const float* tem_emb = (const float*)d_in[10];
    const float* W_ih    = (const float*)d_in[11];
    const float* W_hh    = (const float*)d_in[12];
    const float* b_ih    = (const float*)d_in[13];
    const float* b_hh    = (const float*)d_in[14];
    float* out = (float*)d_out;
    float* xg  = (float*)d_ws;  // 532*512 floats = 1.06 MB of ws

    precompute_xg<<<NROWS / XRPB, 512, 0, stream>>>(
        rel_emb, tem_emb, W_ih, b_ih, b_hh, xg);
    lstm_score<<<BATCH / BT, 128, 0, stream>>>(
        pos_h, pos_t, pos_r, pos_tem, neg_h, neg_t, ent_emb, W_hh, xg, out);
}